// Round 9
// baseline (223.696 us; speedup 1.0000x reference)
//
#include <hip/hip_runtime.h>
#include <hip/hip_bf16.h>

// SocialPooling round 9: single fused kernel (memset + 1 dispatch).
// - blocks 0..63 transpose one W cell -> Wt (bf16, pi-permuted) then release a
//   counter; everyone overlaps staging/cellmap/hoisting and spins on done==64
//   only right before the cell loop.
// - cell loop: R8-verified (stagger by b>>3, double-buffered Wt prefetch,
//   GEMM1' P^T = Ht @ S^T, in-lane reshuffle, GEMM2).
// - epilogue: partials -> threadfence -> last block (of 256, all co-resident:
//   2 blocks/CU capacity) reduces to scale/shift -> flag; all blocks normalize
//   from live LDS Xs and write X once (kills sp_finish's 8MB round-trip).
// Determinism makes cross-XCD stale reads benign (identical values每replay);
// flags are RMW (coherence point) and zeroed by the leading 64B memset.

#define NSEQ 256
#define NTOT (NSEQ*64)
#define EPSV 1e-5f

typedef __attribute__((ext_vector_type(8))) short short8;
typedef __attribute__((ext_vector_type(4))) float f32x4;
typedef unsigned short ushort_t;

__device__ __forceinline__ ushort_t f2b(float f) {
    __hip_bfloat16 h = __float2bfloat16(f);                 // RNE
    return *reinterpret_cast<ushort_t*>(&h);
}
__device__ __forceinline__ int kperm(int k) {               // slot -> source kf
    return ((k >> 5)*2 + ((k & 7) >> 2))*16 + ((k >> 3) & 3)*4 + (k & 3);
}

// d_ws carve (bytes)
#define WS_WT   0               // bf16 Wt[64][64][64]   524288
#define WS_PART 524288          // f32 partials[256][128] 131072
#define WS_GST  655360          // f32 gstats[128] (scale,shift)
#define WS_FLG  656384          // u32 flags[16]: 0=done_cells 1=fin_count 2=stats_flag

// LDS carve (bytes): staging {Ht u16[64][72]@0, cm@9216, pos@13312} and
// transpose Tl f32[64][68]@0 (17408) both live in the Xs0 region [0,17408).
#define SM_CM   9216
#define SM_POS  13312
#define SM_XS1  17408
#define SM_RED  34816           // 2048: red1/red2; reused: redsum[512]; sc/sh[128]
#define SM_FLGL 36864
#define SM_TOT  36880

__global__ __launch_bounds__(512, 2) void sp_one(
    const float* __restrict__ h, const float* __restrict__ pos,
    const float* __restrict__ W, const float* __restrict__ bvec,
    const float* __restrict__ gamma, const float* __restrict__ beta,
    float* __restrict__ X, char* __restrict__ ws)
{
    short*    Wt       = (short*)(ws + WS_WT);
    float*    partials = (float*)(ws + WS_PART);
    float*    gstats   = (float*)(ws + WS_GST);
    unsigned* flg      = (unsigned*)(ws + WS_FLG);

    __shared__ __align__(16) char smem[SM_TOT];
    ushort_t*      Ht     = (ushort_t*)(smem);
    unsigned char* cm     = (unsigned char*)(smem + SM_CM);
    float*         px     = (float*)(smem + SM_POS);
    float*         py     = px + 64;
    unsigned*      islast = (unsigned*)(smem + SM_FLGL);

    const int b    = blockIdx.x;        // sequence
    const int base = b * 64;
    const int tid  = threadIdx.x;
    const int lane = tid & 63, w = tid >> 6;      // 8 waves; wave owns cells w*8..w*8+7
    const int ln15 = lane & 15, ln4 = lane >> 4;
    const int xph  = (b >> 3) & 7;      // stagger phase: varies WITHIN an XCD

    // ---- Phase T: blocks 0..63 transpose one W cell (verified R3..R8 math) ----
    if (b < 64) {
        float* Tl = (float*)smem;                  // [64][68]
        const float* wg = W + (size_t)b*4096;
        #pragma unroll
        for (int m = 0; m < 2; ++m) {
            int c = m*512 + tid;                   // 1024 f32x4 chunks
            int k = c >> 4, t0 = (c & 15)*4;
            *(f32x4*)(Tl + k*68 + t0) = *(const f32x4*)(wg + k*64 + t0);
        }
        __syncthreads();
        {
            int col = tid >> 3, k0 = (tid & 7)*8;  // 512 short8 chunks
            short8 o;
            #pragma unroll
            for (int i2 = 0; i2 < 8; ++i2)
                o[i2] = (short)f2b(Tl[kperm(k0 + i2)*68 + col]);
            *(short8*)(Wt + ((size_t)(b*64 + col)*64 + k0)) = o;
        }
        __threadfence();
        __syncthreads();
        if (tid == 0) atomicAdd(&flg[0], 1u);
        __syncthreads();                           // Tl region free before staging
    }

    // ---- staging: pos + H transposed (Ht[kf][j] = bf16(H[j][kf])) ----
    if (tid < 64) { px[tid] = pos[(base + tid)*2]; py[tid] = pos[(base + tid)*2 + 1]; }
    for (int m = 0; m < 2; ++m) {
        int c = m*512 + tid;
        int j = c >> 4, t0 = (c & 15)*4;
        f32x4 v = *(const f32x4*)(h + (size_t)(base + j)*64 + t0);
        #pragma unroll
        for (int u = 0; u < 4; ++u) Ht[(t0 + u)*72 + j] = f2b(v[u]);
    }
    __syncthreads();

    // ---- cellmap: cm[i][j] = cell 0..63 if valid else 255 (verified R1..R8) ----
    for (int m = 0; m < 8; ++m) {
        int p = m*512 + tid;
        int i = p >> 6, j = p & 63;
        unsigned char val = 255;
        if (i != j) {
            float ax = px[i], ay = py[i], ox = px[j], oy = py[j];
            float tlx = ax - 1.0f, tly = ay + 1.0f, brx = ax + 1.0f, bry = ay - 1.0f;
            bool oob = (ox >= brx) | (ox <= tlx) | (oy >= tly) | (oy <= bry);
            if (!oob) {
                int g = (int)(floorf((ox - tlx)*4.0f) + floorf((tly - oy)*4.0f)*8.0f);
                g = g < 0 ? 0 : (g > 63 ? 63 : g);
                val = (unsigned char)g;
            }
        }
        cm[i*64 + j] = val;
    }
    __syncthreads();

    // ---- hoist GEMM1' A-frags (H^T rows) + full cellmap ----
    short8 hf2[4][2];
    #pragma unroll
    for (int mt = 0; mt < 4; ++mt)
        #pragma unroll
        for (int kt2 = 0; kt2 < 2; ++kt2)
            hf2[mt][kt2] = *(const short8*)(Ht + (mt*16 + ln15)*72 + kt2*32 + ln4*8);
    unsigned cmv[4][2][2];
    #pragma unroll
    for (int rt = 0; rt < 4; ++rt)
        #pragma unroll
        for (int kt = 0; kt < 2; ++kt) {
            const unsigned* cp = (const unsigned*)(cm + (rt*16 + ln15)*64 + kt*32 + ln4*8);
            cmv[rt][kt][0] = cp[0]; cmv[rt][kt][1] = cp[1];
        }

    f32x4 acc[4][4];
    #pragma unroll
    for (int rt = 0; rt < 4; ++rt)
        #pragma unroll
        for (int nt = 0; nt < 4; ++nt) acc[rt][nt] = (f32x4){0.f,0.f,0.f,0.f};

    // ---- wait for Wt ready (all 256 blocks co-resident; transposers done soon) ----
    if (tid == 0) { while (atomicAdd(&flg[0], 0u) < 64u) __builtin_amdgcn_s_sleep(8); }
    __syncthreads();
    __threadfence();

    auto load_cell = [&](short8 (&bw)[2][4], int cidx) {
        const int g = w*8 + ((cidx + xph) & 7);
        const short* wg = Wt + (size_t)g*4096;
        #pragma unroll
        for (int kt = 0; kt < 2; ++kt)
            #pragma unroll
            for (int nt = 0; nt < 4; ++nt)
                bw[kt][nt] = *(const short8*)(wg + (nt*16 + ln15)*64 + kt*32 + ln4*8);
    };
    auto compute_cell = [&](const short8 (&bw)[2][4], int cidx) {
        const int g = w*8 + ((cidx + xph) & 7);
        #pragma unroll
        for (int rt = 0; rt < 4; ++rt) {
            short8 sf[2];
            #pragma unroll
            for (int kt = 0; kt < 2; ++kt)
                #pragma unroll
                for (int u = 0; u < 8; ++u) {
                    unsigned byte = ((u < 4 ? cmv[rt][kt][0] >> (8*u)
                                           : cmv[rt][kt][1] >> (8*(u-4))) & 255u);
                    sf[kt][u] = (byte == (unsigned)g) ? (short)0x3F80 : (short)0;
                }
            f32x4 pt[4];
            #pragma unroll
            for (int mt = 0; mt < 4; ++mt) pt[mt] = (f32x4){0.f,0.f,0.f,0.f};
            #pragma unroll
            for (int kt2 = 0; kt2 < 2; ++kt2)
                #pragma unroll
                for (int mt = 0; mt < 4; ++mt)
                    pt[mt] = __builtin_amdgcn_mfma_f32_16x16x32_bf16(hf2[mt][kt2], sf[kt2], pt[mt], 0, 0, 0);
            #pragma unroll
            for (int kt = 0; kt < 2; ++kt) {
                short8 af;
                #pragma unroll
                for (int r = 0; r < 4; ++r) {
                    af[r]     = (short)f2b(pt[2*kt    ][r]);
                    af[4 + r] = (short)f2b(pt[2*kt + 1][r]);
                }
                #pragma unroll
                for (int nt = 0; nt < 4; ++nt)
                    acc[rt][nt] = __builtin_amdgcn_mfma_f32_16x16x32_bf16(af, bw[kt][nt], acc[rt][nt], 0, 0, 0);
            }
        }
    };

    short8 bwA[2][4], bwB[2][4];
    load_cell(bwA, 0);
    #pragma unroll
    for (int cc = 0; cc < 8; cc += 2) {
        if (cc + 1 < 8) load_cell(bwB, cc + 1);
        compute_cell(bwA, cc);
        if (cc + 2 < 8) load_cell(bwA, cc + 2);
        if (cc + 1 < 8) compute_cell(bwB, cc + 1);
    }
    __syncthreads();                                 // staging reads all hoisted

    // ---- 4-step two-buffer combine (verified R8) ----
    float* Xs0 = (float*)smem;
    float* Xs1 = (float*)(smem + SM_XS1);
    for (int step = 0; step < 4; ++step) {
        if ((w & 3) == step) {
            float* Xs = (w < 4) ? Xs0 : Xs1;
            #pragma unroll
            for (int rt = 0; rt < 4; ++rt)
                #pragma unroll
                for (int nt = 0; nt < 4; ++nt)
                    #pragma unroll
                    for (int r = 0; r < 4; ++r) {
                        int row = rt*16 + ln4*4 + r; // C/D: col=lane&15, row=(lane>>4)*4+reg
                        int col = nt*16 + ln15;
                        if (step == 0) Xs[row*68 + col]  = acc[rt][nt][r];
                        else           Xs[row*68 + col] += acc[rt][nt][r];
                    }
        }
        __syncthreads();
    }

    // ---- per-block column sum/sumsq (with bias) -> partials[b][128] ----
    {
        float* red1 = (float*)(smem + SM_RED);       // [4][64]
        float* red2 = red1 + 256;
        if (tid < 256) {
            int col = tid & 63, rg = tid >> 6;
            float bc = bvec[col], s1 = 0.f, s2 = 0.f;
            for (int ii = 0; ii < 16; ++ii) {
                int o = (rg*16 + ii)*68 + col;
                float xv = Xs0[o] + Xs1[o] + bc;
                s1 += xv; s2 += xv*xv;
            }
            red1[rg*64 + col] = s1;
            red2[rg*64 + col] = s2;
        }
        __syncthreads();
        if (tid < 128) {
            int hs = tid >> 6, c2 = tid & 63;
            const float* r0 = hs ? red2 : red1;
            float v = r0[c2] + r0[64 + c2] + r0[128 + c2] + r0[192 + c2];
            partials[(size_t)b*128 + hs*64 + c2] = v;
        }
    }
    __threadfence();
    __syncthreads();
    if (tid == 0) *islast = (atomicAdd(&flg[1], 1u) == NSEQ - 1u) ? 1u : 0u;
    __syncthreads();

    // ---- last block: reduce 256 partials -> scale/shift -> flag ----
    if (*islast) {
        __threadfence();
        float* redsum = (float*)(smem + SM_RED);     // [4][128]
        const int slot = tid & 127, quarter = tid >> 7;
        const volatile float* pp = partials;
        float v = 0.f;
        for (int bb = 0; bb < 64; ++bb)
            v += pp[(size_t)(quarter*64 + bb)*128 + slot];
        redsum[quarter*128 + slot] = v;
        __syncthreads();
        if (tid < 128) {
            float t = redsum[tid] + redsum[128+tid] + redsum[256+tid] + redsum[384+tid];
            redsum[tid] = t;                         // safe: thread t writes only index t
        }
        __syncthreads();
        if (tid < 64) {
            const float inv_n = 1.0f / (float)NTOT;
            float mu  = redsum[tid] * inv_n;
            float var = redsum[64 + tid] * inv_n - mu*mu;
            float sc  = gamma[tid] / sqrtf(var + EPSV);
            gstats[tid]      = sc;
            gstats[64 + tid] = beta[tid] - mu*sc;
        }
        __threadfence();
        __syncthreads();
        if (tid == 0) atomicExch(&flg[2], 1u);
    }

    // ---- all blocks: wait for stats, normalize from live LDS, write X once ----
    if (tid == 0) { while (atomicAdd(&flg[2], 0u) == 0u) __builtin_amdgcn_s_sleep(8); }
    __syncthreads();
    __threadfence();
    float* scsh = (float*)(smem + SM_RED);           // [128]: scale, shift
    if (tid < 128) scsh[tid] = ((const volatile float*)gstats)[tid];
    __syncthreads();
    {
        const int row = tid >> 3, c0 = (tid & 7)*8;
        float* xg = X + (size_t)(base + row)*64 + c0;
        #pragma unroll
        for (int q = 0; q < 2; ++q) {
            f32x4 v;
            #pragma unroll
            for (int u = 0; u < 4; ++u) {
                int cc2 = c0 + q*4 + u;
                int o   = row*68 + cc2;
                float xv = Xs0[o] + Xs1[o] + bvec[cc2];
                v[u] = fmaxf(xv*scsh[cc2] + scsh[64 + cc2], 0.0f);
            }
            *(f32x4*)(xg + q*4) = v;
        }
    }
}

extern "C" void kernel_launch(void* const* d_in, const int* in_sizes, int n_in,
                              void* d_out, int out_size, void* d_ws, size_t ws_size,
                              hipStream_t stream)
{
    const float* h     = (const float*)d_in[0];
    // d_in[1] seq_start_end: provably uniform (reference only uses N//nseq)
    const float* pos   = (const float*)d_in[2];
    const float* W     = (const float*)d_in[3];
    const float* bvec  = (const float*)d_in[4];
    const float* gamma = (const float*)d_in[5];
    const float* beta  = (const float*)d_in[6];

    float* X  = (float*)d_out;
    char*  ws = (char*)d_ws;

    hipMemsetAsync(ws + WS_FLG, 0, 64, stream);      // zero flags (poisoned 0xAA)
    sp_one<<<NSEQ, 512, 0, stream>>>(h, pos, W, bvec, gamma, beta, X, ws);
}

// Round 10
// 106.180 us; speedup vs baseline: 2.1068x; 2.1068x over previous
//
#include <hip/hip_runtime.h>
#include <hip/hip_bf16.h>

// SocialPooling round 10: revert to R8 (verified 104us) + packed bf16 converts
// in the GEMM2 A-frag build (v_cvt_pk_bf16_f32 via __float22bfloat162_rn).
// R9 lesson: single-kernel phases with device-scope fences/spins cost ~115us
// after the harness's 268MB dirty-L2 ws poison -> keep the 3-dispatch pipeline.
// Numerics identical to R6..R9 (pi-permuted Wt, GEMM1' P^T = Ht @ S^T, in-lane
// reshuffle, f32 stats): absmax expected exactly 0.03125.

#define NSEQ 256
#define NTOT (NSEQ*64)
#define EPSV 1e-5f

typedef __attribute__((ext_vector_type(8))) short short8;
typedef __attribute__((ext_vector_type(4))) float f32x4;
typedef unsigned short ushort_t;

__device__ __forceinline__ ushort_t f2b(float f) {
    __hip_bfloat16 h = __float2bfloat16(f);                 // RNE
    return *reinterpret_cast<ushort_t*>(&h);
}
__device__ __forceinline__ unsigned pk2(float a, float b) { // 2x f32 -> packed bf16x2 (RNE)
    __hip_bfloat162 t = __float22bfloat162_rn(float2{a, b});
    return *reinterpret_cast<unsigned*>(&t);
}
__device__ __forceinline__ int kperm(int k) {               // slot -> source kf
    return ((k >> 5)*2 + ((k & 7) >> 2))*16 + ((k >> 3) & 3)*4 + (k & 3);
}

// ---------------- K0: W -> bf16 Wt'[g][col][slot] = W[g*64 + pi(slot)][col] ----------------
__global__ __launch_bounds__(256) void sp_transpose(
    const float* __restrict__ W, short* __restrict__ Wt)
{
    __shared__ __align__(16) float Tl[64*68];
    const int b = blockIdx.x, tid = threadIdx.x;
    const float* wg = W + (size_t)b*4096;
    for (int m = 0; m < 4; ++m) {
        int c = m*256 + tid;
        int k = c >> 4, t0 = (c & 15)*4;
        *(f32x4*)(Tl + k*68 + t0) = *(const f32x4*)(wg + k*64 + t0);
    }
    __syncthreads();
    for (int m = 0; m < 2; ++m) {
        int q = m*256 + tid;
        int col = q >> 3, k0 = (q & 7)*8;
        short8 o;
        #pragma unroll
        for (int i2 = 0; i2 < 8; ++i2)
            o[i2] = (short)f2b(Tl[kperm(k0 + i2)*68 + col]);
        *(short8*)(Wt + ((size_t)(b*64 + col)*64 + k0)) = o;
    }
}

// ---------------- K1: main ----------------
// LDS: staging {Ht u16[64][72]@0 9216, cm@9216 4096, pos@13312 512} (aliased by)
//      epilogue {Xs0 f32[64][68]@0, Xs1@17408, red[2][4][64]@34816} tot 36864
#define SM_CM   9216
#define SM_POS  13312
#define SM_XS1  17408
#define SM_RED  34816
#define SM_TOT  36864

__global__ __launch_bounds__(512, 2) void sp_main(
    const float* __restrict__ h, const float* __restrict__ pos,
    const short* __restrict__ Wt, const float* __restrict__ bvec,
    float* __restrict__ X, float* __restrict__ partials)
{
    __shared__ __align__(16) char smem[SM_TOT];
    ushort_t*      Ht = (ushort_t*)(smem);
    unsigned char* cm = (unsigned char*)(smem + SM_CM);
    float*         px = (float*)(smem + SM_POS);
    float*         py = px + 64;

    const int b    = blockIdx.x;        // sequence
    const int base = b * 64;
    const int tid  = threadIdx.x;
    const int lane = tid & 63, w = tid >> 6;      // 8 waves; wave owns cells w*8..w*8+7
    const int ln15 = lane & 15, ln4 = lane >> 4;
    const int xph  = (b >> 3) & 7;      // stagger phase: varies WITHIN an XCD (R8 win)

    if (tid < 64) { px[tid] = pos[(base + tid)*2]; py[tid] = pos[(base + tid)*2 + 1]; }
    // stage H transposed: Ht[kf][j] = bf16(H[j][kf])
    for (int m = 0; m < 2; ++m) {
        int c = m*512 + tid;
        int j = c >> 4, t0 = (c & 15)*4;
        f32x4 v = *(const f32x4*)(h + (size_t)(base + j)*64 + t0);
        #pragma unroll
        for (int u = 0; u < 4; ++u) Ht[(t0 + u)*72 + j] = f2b(v[u]);
    }
    __syncthreads();

    // cellmap: cm[i][j] = cell 0..63 if valid pair else 255 (verified R1..R8)
    for (int m = 0; m < 8; ++m) {
        int p = m*512 + tid;
        int i = p >> 6, j = p & 63;
        unsigned char val = 255;
        if (i != j) {
            float ax = px[i], ay = py[i], ox = px[j], oy = py[j];
            float tlx = ax - 1.0f, tly = ay + 1.0f, brx = ax + 1.0f, bry = ay - 1.0f;
            bool oob = (ox >= brx) | (ox <= tlx) | (oy >= tly) | (oy <= bry);
            if (!oob) {
                int g = (int)(floorf((ox - tlx)*4.0f) + floorf((tly - oy)*4.0f)*8.0f);
                g = g < 0 ? 0 : (g > 63 ? 63 : g);
                val = (unsigned char)g;
            }
        }
        cm[i*64 + j] = val;
    }
    __syncthreads();

    // hoist GEMM1' A-frags (H^T rows) and the full cellmap for all 4 row-tiles
    short8 hf2[4][2];
    #pragma unroll
    for (int mt = 0; mt < 4; ++mt)
        #pragma unroll
        for (int kt2 = 0; kt2 < 2; ++kt2)
            hf2[mt][kt2] = *(const short8*)(Ht + (mt*16 + ln15)*72 + kt2*32 + ln4*8);
    unsigned cmv[4][2][2];
    #pragma unroll
    for (int rt = 0; rt < 4; ++rt)
        #pragma unroll
        for (int kt = 0; kt < 2; ++kt) {
            const unsigned* cp = (const unsigned*)(cm + (rt*16 + ln15)*64 + kt*32 + ln4*8);
            cmv[rt][kt][0] = cp[0]; cmv[rt][kt][1] = cp[1];
        }

    f32x4 acc[4][4];                    // [rt][nt]
    #pragma unroll
    for (int rt = 0; rt < 4; ++rt)
        #pragma unroll
        for (int nt = 0; nt < 4; ++nt) acc[rt][nt] = (f32x4){0.f,0.f,0.f,0.f};

    auto load_cell = [&](short8 (&bw)[2][4], int cidx) {
        const int g = w*8 + ((cidx + xph) & 7);
        const short* wg = Wt + (size_t)g*4096;
        #pragma unroll
        for (int kt = 0; kt < 2; ++kt)
            #pragma unroll
            for (int nt = 0; nt < 4; ++nt)
                bw[kt][nt] = *(const short8*)(wg + (nt*16 + ln15)*64 + kt*32 + ln4*8);
    };
    auto compute_cell = [&](const short8 (&bw)[2][4], int cidx) {
        const int g = w*8 + ((cidx + xph) & 7);
        #pragma unroll
        for (int rt = 0; rt < 4; ++rt) {
            short8 sf[2];
            #pragma unroll
            for (int kt = 0; kt < 2; ++kt)
                #pragma unroll
                for (int u = 0; u < 8; ++u) {
                    unsigned byte = ((u < 4 ? cmv[rt][kt][0] >> (8*u)
                                           : cmv[rt][kt][1] >> (8*(u-4))) & 255u);
                    sf[kt][u] = (byte == (unsigned)g) ? (short)0x3F80 : (short)0;
                }
            f32x4 pt[4];
            #pragma unroll
            for (int mt = 0; mt < 4; ++mt) pt[mt] = (f32x4){0.f,0.f,0.f,0.f};
            #pragma unroll
            for (int kt2 = 0; kt2 < 2; ++kt2)
                #pragma unroll
                for (int mt = 0; mt < 4; ++mt)
                    pt[mt] = __builtin_amdgcn_mfma_f32_16x16x32_bf16(hf2[mt][kt2], sf[kt2], pt[mt], 0, 0, 0);
            #pragma unroll
            for (int kt = 0; kt < 2; ++kt) {
                union { short8 s; unsigned u4[4]; } af;     // packed bf16 converts (R10)
                af.u4[0] = pk2(pt[2*kt    ][0], pt[2*kt    ][1]);
                af.u4[1] = pk2(pt[2*kt    ][2], pt[2*kt    ][3]);
                af.u4[2] = pk2(pt[2*kt + 1][0], pt[2*kt + 1][1]);
                af.u4[3] = pk2(pt[2*kt + 1][2], pt[2*kt + 1][3]);
                #pragma unroll
                for (int nt = 0; nt < 4; ++nt)
                    acc[rt][nt] = __builtin_amdgcn_mfma_f32_16x16x32_bf16(af.s, bw[kt][nt], acc[rt][nt], 0, 0, 0);
            }
        }
    };

    // software-pipelined cell loop: prefetch next cell's Wt frags during compute
    short8 bwA[2][4], bwB[2][4];
    load_cell(bwA, 0);
    #pragma unroll
    for (int cc = 0; cc < 8; cc += 2) {
        if (cc + 1 < 8) load_cell(bwB, cc + 1);
        compute_cell(bwA, cc);
        if (cc + 2 < 8) load_cell(bwA, cc + 2);
        if (cc + 1 < 8) compute_cell(bwB, cc + 1);
    }
    __syncthreads();                                 // staging reads all hoisted

    // 4-step two-buffer combine: waves 0-3 -> Xs0, waves 4-7 -> Xs1 (parallel)
    float* Xs0 = (float*)smem;
    float* Xs1 = (float*)(smem + SM_XS1);
    for (int step = 0; step < 4; ++step) {
        if ((w & 3) == step) {
            float* Xs = (w < 4) ? Xs0 : Xs1;
            #pragma unroll
            for (int rt = 0; rt < 4; ++rt)
                #pragma unroll
                for (int nt = 0; nt < 4; ++nt)
                    #pragma unroll
                    for (int r = 0; r < 4; ++r) {
                        int row = rt*16 + ln4*4 + r; // C/D: col=lane&15, row=(lane>>4)*4+reg
                        int col = nt*16 + ln15;
                        if (step == 0) Xs[row*68 + col]  = acc[rt][nt][r];
                        else           Xs[row*68 + col] += acc[rt][nt][r];
                    }
        }
        __syncthreads();
    }

    // write X + bias (f32x4 coalesced): 512 threads x 8 floats
    {
        const int row = tid >> 3, c0 = (tid & 7)*8;
        float* xg = X + (size_t)(base + row)*64 + c0;
        #pragma unroll
        for (int q = 0; q < 2; ++q) {
            f32x4 v;
            #pragma unroll
            for (int u = 0; u < 4; ++u) {
                int o = row*68 + c0 + q*4 + u;
                v[u] = Xs0[o] + Xs1[o] + bvec[c0 + q*4 + u];
            }
            *(f32x4*)(xg + q*4) = v;
        }
    }

    // per-block column sum / sumsq (with bias) over 64 rows
    {
        float* red1 = (float*)(smem + SM_RED);       // [4][64]
        float* red2 = red1 + 256;
        if (tid < 256) {
            int col = tid & 63, rg = tid >> 6;
            float bc = bvec[col], s1 = 0.f, s2 = 0.f;
            for (int ii = 0; ii < 16; ++ii) {
                int o = (rg*16 + ii)*68 + col;
                float xv = Xs0[o] + Xs1[o] + bc;
                s1 += xv; s2 += xv*xv;
            }
            red1[rg*64 + col] = s1;
            red2[rg*64 + col] = s2;
        }
        __syncthreads();
        if (tid < 128) {
            int hs = tid >> 6, c2 = tid & 63;
            const float* r0 = hs ? red2 : red1;
            float v = r0[c2] + r0[64 + c2] + r0[128 + c2] + r0[192 + c2];
            partials[(size_t)b*128 + hs*64 + c2] = v; // [block][slot]
        }
    }
}

// ---------------- K2: redundant stats reduce + normalize + ReLU (verified R4+) ----------------
__global__ __launch_bounds__(256) void sp_finish(
    float* __restrict__ X, const float* __restrict__ partials,
    const float* __restrict__ gamma, const float* __restrict__ beta)
{
    __shared__ float sp0[128], sp1[128];
    __shared__ float scale[64], shift[64];
    const int b = blockIdx.x, tid = threadIdx.x;

    {   // sum 256 block-partials; coalesced along slot
        const int slot = tid & 127, hb = tid >> 7;
        float v = 0.f;
        const float* p = partials + (size_t)hb*128*128 + slot;
        #pragma unroll 4
        for (int bb = 0; bb < 128; ++bb) v += p[(size_t)bb*128];
        (hb ? sp1 : sp0)[slot] = v;
    }
    __syncthreads();
    if (tid < 64) {
        const float inv_n = 1.0f / (float)NTOT;
        float s1 = sp0[tid] + sp1[tid];
        float s2 = sp0[64 + tid] + sp1[64 + tid];
        float mu  = s1 * inv_n;
        float var = s2 * inv_n - mu*mu;
        float sc  = gamma[tid] / sqrtf(var + EPSV);
        scale[tid] = sc;
        shift[tid] = beta[tid] - mu*sc;
    }
    __syncthreads();
    #pragma unroll
    for (int q = 0; q < 4; ++q) {
        size_t idx4 = (size_t)b*1024 + q*256 + tid;  // f32x4 units
        f32x4 v = ((f32x4*)X)[idx4];
        int c0 = ((int)idx4*4) & 63;
        #pragma unroll
        for (int u = 0; u < 4; ++u)
            v[u] = fmaxf(v[u]*scale[c0 + u] + shift[c0 + u], 0.0f);
        ((f32x4*)X)[idx4] = v;
    }
}

extern "C" void kernel_launch(void* const* d_in, const int* in_sizes, int n_in,
                              void* d_out, int out_size, void* d_ws, size_t ws_size,
                              hipStream_t stream)
{
    const float* h     = (const float*)d_in[0];
    // d_in[1] seq_start_end: provably uniform (reference only uses N//nseq)
    const float* pos   = (const float*)d_in[2];
    const float* W     = (const float*)d_in[3];
    const float* bvec  = (const float*)d_in[4];
    const float* gamma = (const float*)d_in[5];
    const float* beta  = (const float*)d_in[6];

    float* X        = (float*)d_out;
    short* Wt       = (short*)d_ws;                  // 512 KB bf16 W' (k-permuted)
    float* partials = (float*)((char*)d_ws + 524288);// 256*128*4 = 128 KB

    sp_transpose<<<64,   256, 0, stream>>>(W, Wt);
    sp_main     <<<NSEQ, 512, 0, stream>>>(h, pos, Wt, bvec, X, partials);
    sp_finish   <<<NSEQ, 256, 0, stream>>>(X, partials, gamma, beta);
}